// Round 7
// baseline (362.469 us; speedup 1.0000x reference)
//
#include <hip/hip_runtime.h>
#include <hip/hip_fp16.h>

#define HH 128
#define WW 128
#define NPIX (HH*WW)
#define NB 8
#define NHEADS 6
#define HD 32
#define SCALE 0.17677669529663687f

typedef _Float16 h2 __attribute__((ext_vector_type(2)));
typedef __fp16 g2 __attribute__((ext_vector_type(2)));
typedef _Float16 f16x4 __attribute__((ext_vector_type(4)));
typedef _Float16 f16x8 __attribute__((ext_vector_type(8)));
typedef float f4 __attribute__((ext_vector_type(4)));

#define LDK 40    // na2d/oproj padded k-stride (unchanged)
#define LDKP 36   // proj k-stride: 72B rows = 18 dwords, gcd(18,32)=2 -> ~free reads, 4-way staged writes

union U8 { f16x4 q[2]; f16x8 v; };
union U4 { g2 p2[2]; f16x4 v4; };

// ---------------- MFMA projection v2 ----------------
// C^T layout: mfma(A=W_frag, B=pixel_frag) -> lane&15 = pixel, rows = channels.
// Each lane then owns 4 CONSECUTIVE channels of one pixel -> packed 8B stores.
// Grid: 3072 1D blocks. XCD swizzle: per XCD, 128 q-blocks then 128 interleaved (k,v) pairs
// so the k-block and v-block for the same ctx tile run on the same XCD (ctx L2-shared).
__global__ __launch_bounds__(512) void proj_mfma(
    const float* __restrict__ x, const float* __restrict__ ctx,
    const float* __restrict__ Wq, const float* __restrict__ Wk, const float* __restrict__ Wv,
    const float* __restrict__ bq, const float* __restrict__ bk, const float* __restrict__ bv,
    _Float16* __restrict__ qh, _Float16* __restrict__ kh, _Float16* __restrict__ vh)
{
    int bid = blockIdx.x;
    int xcd = bid & 7;
    int i = bid >> 3;                 // 0..383
    int z, xb;
    if (i < 128) { z = 0; xb = xcd * 128 + i; }
    else { int j = i - 128; z = 1 + (j & 1); xb = xcd * 128 + (j >> 1); }

    const float* A  = (z == 0) ? x : ctx;
    const float* Wt = (z == 0) ? Wq : (z == 1 ? Wk : Wv);
    const float* bias = (z == 0) ? bq : (z == 1 ? bk : bv);
    _Float16* outp = (z == 0) ? qh : (z == 1 ? kh : vh);
    float scale = (z == 0) ? SCALE : 1.f;

    __shared__ _Float16 As[128][LDKP];
    __shared__ _Float16 Ws[192][LDKP];

    int t = threadIdx.x;
    int m0 = xb * 128;
    int b  = m0 / NPIX;
    int p0 = m0 % NPIX;
    const float* Ab = A + (size_t)b * 192 * NPIX + p0;

    int lane = t & 63;
    int wv = t >> 6;          // wave -> 16-pixel tile
    int lq = lane & 15;       // pixel within tile (C col)
    int lk = lane >> 4;       // k-chunk / C row quad

    f4 acc[12] = {};

    for (int ks = 0; ks < 6; ks++) {
        int k0 = ks * 32;
        // stage A: 128 pix x 16 c-pairs, cvt_pkrtz -> 4B writes
        #pragma unroll
        for (int ii = 0; ii < 4; ii++) {
            int s = t + ii * 512;
            int cp = s >> 7, p = s & 127;
            float a0 = Ab[(size_t)(k0 + 2 * cp) * NPIX + p];
            float a1 = Ab[(size_t)(k0 + 2 * cp + 1) * NPIX + p];
            *(g2*)&As[p][2 * cp] = __builtin_amdgcn_cvt_pkrtz(a0, a1);
        }
        // stage W^T: Ws[n][c] = W[k0+c][n], 192 n x 16 c-pairs
        #pragma unroll
        for (int ii = 0; ii < 6; ii++) {
            int s = t + ii * 512;
            int n = s % 192, cp = s / 192;
            float w0 = Wt[(size_t)(k0 + 2 * cp) * 192 + n];
            float w1 = Wt[(size_t)(k0 + 2 * cp + 1) * 192 + n];
            *(g2*)&Ws[n][2 * cp] = __builtin_amdgcn_cvt_pkrtz(w0, w1);
        }
        __syncthreads();

        U8 pf;
        pf.q[0] = *(const f16x4*)&As[wv * 16 + lq][lk * 8];
        pf.q[1] = *(const f16x4*)&As[wv * 16 + lq][lk * 8 + 4];
        #pragma unroll
        for (int nt = 0; nt < 12; nt++) {
            U8 wf;
            wf.q[0] = *(const f16x4*)&Ws[nt * 16 + lq][lk * 8];
            wf.q[1] = *(const f16x4*)&Ws[nt * 16 + lq][lk * 8 + 4];
            acc[nt] = __builtin_amdgcn_mfma_f32_16x16x32_f16(wf.v, pf.v, acc[nt], 0, 0, 0);
        }
        __syncthreads();
    }

    // epilogue: lane owns pixel p, channels n0..n0+3 (consecutive, within one head) -> 8B stores
    int p = p0 + wv * 16 + lq;
    #pragma unroll
    for (int nt = 0; nt < 12; nt++) {
        int n0 = nt * 16 + lk * 4;
        int g = n0 >> 5, d0 = n0 & 31;
        f4 v = acc[nt];
        float e0 = (v[0] + bias[n0])     * scale;
        float e1 = (v[1] + bias[n0 + 1]) * scale;
        float e2 = (v[2] + bias[n0 + 2]) * scale;
        float e3 = (v[3] + bias[n0 + 3]) * scale;
        U4 u;
        u.p2[0] = __builtin_amdgcn_cvt_pkrtz(e0, e1);
        u.p2[1] = __builtin_amdgcn_cvt_pkrtz(e2, e3);
        _Float16* dst = outp + ((size_t)(b * NHEADS + g) * NPIX + p) * HD + d0;
        *(f16x4*)dst = u.v4;
    }
}

// ---------------- MFMA neighborhood attention (unchanged from R6) ----------------
#define KS_ELE 33280            // 26*32*40 fp16
#define NA2D_SMEM 134912

template<int K>
__device__ __forceinline__ void na2d_tile(
    const _Float16* __restrict__ qh, const _Float16* __restrict__ kh,
    const _Float16* __restrict__ vh, const float* __restrict__ rpb,
    _Float16* __restrict__ ah, char* smem, int b, int g_head, int hi, int ty, int tx)
{
    constexpr int NS = K / 2;
    constexpr int RW = 2 * K - 1;
    _Float16* Ks = (_Float16*)smem;
    _Float16* Vt = Ks + KS_ELE;
    float* rpbs = (float*)(smem + 2 * KS_ELE * 2);

    int t = threadIdx.x;
    size_t plane = (size_t)(b * NHEADS + g_head) * NPIX;
    int h0 = ty * 16, w0 = tx * 16;
    int rmin = min(max(h0 - NS, 0), HH - K);
    int rtop = min(max(h0 + 15 - NS, 0), HH - K);
    int rows_n = rtop + K - rmin;
    int cwin0 = min(max(w0 - NS, 0), WW - K);
    int ctop = min(max(w0 + 15 - NS, 0), WW - K);
    int cols_n = ctop + K - cwin0;

    for (int i = t; i < RW * RW; i += 512) rpbs[i] = rpb[(size_t)hi * RW * RW + i];

    int ntask = rows_n * 128;
    for (int idx = t; idx < ntask; idx += 512) {
        int row = idx >> 7;
        int key = (idx >> 2) & 31;
        int dc  = idx & 3;
        f16x8 kv = {0,0,0,0,0,0,0,0};
        f16x8 vvv = {0,0,0,0,0,0,0,0};
        if (key < cols_n) {
            size_t pix = plane + (size_t)(rmin + row) * WW + (cwin0 + key);
            kv = *(const f16x8*)&kh[pix * HD + dc * 8];
            vvv = *(const f16x8*)&vh[pix * HD + dc * 8];
        }
        *(f16x8*)&Ks[row * 1280 + key * LDK + dc * 8] = kv;
        int m = 8 * ((key & 15) >> 2) + 4 * (key >> 4) + (key & 3);
        #pragma unroll
        for (int j = 0; j < 8; j++)
            Vt[row * 1280 + (dc * 8 + j) * LDK + m] = vvv[j];
    }
    __syncthreads();

    int lane = t & 63, wid = t >> 6;
    int lq = lane & 15, lg = lane >> 4;
    int wq = w0 + lq;
    int c0q = min(max(wq - NS, 0), WW - K);
    int klo = c0q - cwin0;
    int shiftc = cwin0 - wq + K - 1;
    f4 zf4 = {0.f, 0.f, 0.f, 0.f};

    #pragma unroll 1
    for (int qi = 0; qi < 2; qi++) {
        int qr = wid * 2 + qi;
        int h = h0 + qr;
        int r0q = min(max(h - NS, 0), HH - K);
        int row_base = r0q - rmin;
        f16x8 qf = *(const f16x8*)&qh[(plane + (size_t)h * WW + w0 + lq) * HD + lg * 8];
        f4 acc0 = zf4, acc1 = zf4;
        float lsum = 0.f;

        #pragma unroll 1
        for (int ki = 0; ki < K; ki++) {
            int row = row_base + ki;
            const _Float16* kbase = &Ks[row * 1280 + lg * 8];
            f16x8 a0 = *(const f16x8*)&kbase[lq * LDK];
            f16x8 a1 = *(const f16x8*)&kbase[(16 + lq) * LDK];
            f4 s0 = __builtin_amdgcn_mfma_f32_16x16x32_f16(a0, qf, zf4, 0, 0, 0);
            f4 s1 = __builtin_amdgcn_mfma_f32_16x16x32_f16(a1, qf, zf4, 0, 0, 0);

            int rel_r = r0q + ki - h + K - 1;
            const float* rrow = rpbs + rel_r * RW;
            float pf[2][4];
            #pragma unroll
            for (int c = 0; c < 2; c++) {
                #pragma unroll
                for (int r = 0; r < 4; r++) {
                    int key_local = c * 16 + 4 * lg + r;
                    int rc = key_local + shiftc;
                    rc = min(max(rc, 0), RW - 1);
                    float biasv = rrow[rc];
                    bool valid = (unsigned)(key_local - klo) < (unsigned)K;
                    float sv = (c ? s1[r] : s0[r]) + biasv;
                    float pv = valid ? __expf(sv) : 0.f;
                    pf[c][r] = pv;
                    lsum += pv;
                }
            }
            union { g2 p[4]; f16x8 v; } P;
            P.p[0] = __builtin_amdgcn_cvt_pkrtz(pf[0][0], pf[0][1]);
            P.p[1] = __builtin_amdgcn_cvt_pkrtz(pf[0][2], pf[0][3]);
            P.p[2] = __builtin_amdgcn_cvt_pkrtz(pf[1][0], pf[1][1]);
            P.p[3] = __builtin_amdgcn_cvt_pkrtz(pf[1][2], pf[1][3]);

            const _Float16* vbase = &Vt[row * 1280 + lg * 8];
            f16x8 b0 = *(const f16x8*)&vbase[lq * LDK];
            f16x8 b1 = *(const f16x8*)&vbase[(16 + lq) * LDK];
            acc0 = __builtin_amdgcn_mfma_f32_16x16x32_f16(P.v, b0, acc0, 0, 0, 0);
            acc1 = __builtin_amdgcn_mfma_f32_16x16x32_f16(P.v, b1, acc1, 0, 0, 0);
        }

        lsum += __shfl_xor(lsum, 16);
        lsum += __shfl_xor(lsum, 32);
        float inv = 1.f / lsum;
        _Float16* obase = ah + (plane + (size_t)h * WW + w0) * HD;
        #pragma unroll
        for (int r = 0; r < 4; r++) {
            float ir = __shfl(inv, 4 * lg + r);
            obase[(4 * lg + r) * HD + lq]      = (_Float16)(acc0[r] * ir);
            obase[(4 * lg + r) * HD + lq + 16] = (_Float16)(acc1[r] * ir);
        }
    }
}

__global__ __launch_bounds__(512) void na2d_mfma(
    const _Float16* __restrict__ qh, const _Float16* __restrict__ kh,
    const _Float16* __restrict__ vh,
    const float* __restrict__ rpb0, const float* __restrict__ rpb1,
    const float* __restrict__ rpb2, _Float16* __restrict__ ah)
{
    extern __shared__ char smem[];
    int bid = blockIdx.x;
    int xcd = bid & 7;
    int i = bid >> 3;
    int phase = i >> 7;
    int j = i & 127;
    int lb = xcd * 128 + j;
    int bz = lb >> 6;
    int tile = lb & 63;
    int b = bz >> 1, hi = bz & 1;
    int ty = tile >> 3, tx = tile & 7;
    if (phase == 0)      na2d_tile<7>(qh, kh, vh, rpb0, ah, smem, b, 0 + hi, hi, ty, tx);
    else if (phase == 1) na2d_tile<9>(qh, kh, vh, rpb1, ah, smem, b, 2 + hi, hi, ty, tx);
    else                 na2d_tile<11>(qh, kh, vh, rpb2, ah, smem, b, 4 + hi, hi, ty, tx);
}

// ---------------- MFMA output projection (unchanged from R6) ----------------
__global__ __launch_bounds__(512) void oproj_mfma(
    const _Float16* __restrict__ ah, const float* __restrict__ Wo,
    const float* __restrict__ bo, float* __restrict__ outp)
{
    __shared__ _Float16 Ws[192][LDK];

    int t = threadIdx.x;
    int m0 = blockIdx.x * 128;
    int b  = m0 / NPIX;
    int p0 = m0 % NPIX;

    int lane = t & 63;
    int wid  = t >> 6;
    int wm = wid & 1;
    int wn = wid >> 1;
    int lr = lane & 15;
    int lk = lane >> 4;

    f4 acc[4][3] = {};

    for (int ks = 0; ks < 6; ks++) {
        int k0 = ks * 32;
        #pragma unroll
        for (int i = 0; i < 12; i++) {
            int s = t + i * 512;
            int c = s / 192, n = s - c * 192;
            Ws[n][c] = (_Float16)Wo[(size_t)(k0 + c) * 192 + n];
        }
        __syncthreads();

        const _Float16* abase = ah + (size_t)(b * NHEADS + ks) * NPIX * HD;
        f16x8 af[4], bf[3];
        #pragma unroll
        for (int mi = 0; mi < 4; mi++)
            af[mi] = *(const f16x8*)&abase[(size_t)(p0 + wm * 64 + mi * 16 + lr) * HD + lk * 8];
        #pragma unroll
        for (int ni = 0; ni < 3; ni++)
            bf[ni] = *(const f16x8*)&Ws[wn * 48 + ni * 16 + lr][lk * 8];
        #pragma unroll
        for (int mi = 0; mi < 4; mi++)
            #pragma unroll
            for (int ni = 0; ni < 3; ni++)
                acc[mi][ni] = __builtin_amdgcn_mfma_f32_16x16x32_f16(af[mi], bf[ni], acc[mi][ni], 0, 0, 0);
        __syncthreads();
    }

    #pragma unroll
    for (int ni = 0; ni < 3; ni++) {
        int n = wn * 48 + ni * 16 + lr;
        float bb = bo[n];
        float* obase = outp + ((size_t)b * 192 + n) * NPIX + p0 + wm * 64;
        #pragma unroll
        for (int mi = 0; mi < 4; mi++) {
            f4 v = acc[mi][ni];
            v[0] += bb; v[1] += bb; v[2] += bb; v[3] += bb;
            *(f4*)&obase[mi * 16 + lk * 4] = v;
        }
    }
}

extern "C" void kernel_launch(void* const* d_in, const int* in_sizes, int n_in,
                              void* d_out, int out_size, void* d_ws, size_t ws_size,
                              hipStream_t stream) {
    const float* x    = (const float*)d_in[0];
    const float* ctx  = (const float*)d_in[1];
    const float* Wq   = (const float*)d_in[2];
    const float* bq   = (const float*)d_in[3];
    const float* Wk   = (const float*)d_in[4];
    const float* bk   = (const float*)d_in[5];
    const float* Wv   = (const float*)d_in[6];
    const float* bv   = (const float*)d_in[7];
    const float* Wo   = (const float*)d_in[8];
    const float* bo   = (const float*)d_in[9];
    const float* rpb0 = (const float*)d_in[10];
    const float* rpb1 = (const float*)d_in[11];
    const float* rpb2 = (const float*)d_in[12];

    size_t N = (size_t)NB * NHEADS * NPIX * HD;
    _Float16* qh = (_Float16*)d_ws;
    _Float16* kh = qh + N;
    _Float16* vh = kh + N;
    _Float16* ah = vh + N;
    float* outp = (float*)d_out;

    (void)hipFuncSetAttribute((const void*)na2d_mfma,
                              hipFuncAttributeMaxDynamicSharedMemorySize, NA2D_SMEM);

    proj_mfma<<<3072, 512, 0, stream>>>(x, ctx, Wq, Wk, Wv, bq, bk, bv, qh, kh, vh);
    na2d_mfma<<<3072, 512, NA2D_SMEM, stream>>>(qh, kh, vh, rpb0, rpb1, rpb2, ah);
    oproj_mfma<<<1024, 512, 0, stream>>>(ah, Wo, bo, outp);
}

// Round 8
// 280.283 us; speedup vs baseline: 1.2932x; 1.2932x over previous
//
#include <hip/hip_runtime.h>
#include <hip/hip_fp16.h>

#define HH 128
#define WW 128
#define NPIX (HH*WW)
#define NB 8
#define NHEADS 6
#define HD 32
#define SCALE 0.17677669529663687f

typedef _Float16 h2 __attribute__((ext_vector_type(2)));
typedef __fp16 g2 __attribute__((ext_vector_type(2)));
typedef _Float16 f16x4 __attribute__((ext_vector_type(4)));
typedef _Float16 f16x8 __attribute__((ext_vector_type(8)));
typedef float f4 __attribute__((ext_vector_type(4)));

#define LDK 40    // na2d/oproj padded k-stride
union U4 { g2 p2[2]; f16x4 v4; };

// ---------------- prep: WT[z][n][k] fp16 from W[z][k][n] fp32 (221KB total) ----------------
__global__ __launch_bounds__(512) void prep_wt(
    const float* __restrict__ Wq, const float* __restrict__ Wk,
    const float* __restrict__ Wv, _Float16* __restrict__ wt)
{
    int idx = blockIdx.x * 512 + threadIdx.x;      // 3*36864 total
    int mat = idx / 36864, rem = idx % 36864;
    int k = rem / 192, n = rem % 192;              // consecutive idx -> consecutive n: coalesced read
    const float* W = mat == 0 ? Wq : (mat == 1 ? Wk : Wv);
    wt[(size_t)mat * 36864 + (size_t)n * 192 + k] = (_Float16)W[(size_t)k * 192 + n];
}

// ---------------- MFMA projection v3 ----------------
// Only A (pixels) staged in LDS (10KB). W fragments read DIRECTLY from precomputed
// fp16 WT[n][k] (L1/L2-resident, fragment-shaped 16B loads). Swapped operands:
// mfma(A=W_frag rows=channels, B=pixel_frag cols=pixels) -> lane owns 4 consecutive
// channels of one pixel -> packed 8B stores. XCD pairing: per XCD 128 q-blocks then
// 128 interleaved (k,v) pairs sharing ctx via L2.
__global__ __launch_bounds__(512, 2) void proj_mfma(
    const float* __restrict__ x, const float* __restrict__ ctx,
    const _Float16* __restrict__ wt,
    const float* __restrict__ bq, const float* __restrict__ bk, const float* __restrict__ bv,
    _Float16* __restrict__ qh, _Float16* __restrict__ kh, _Float16* __restrict__ vh)
{
    int bid = blockIdx.x;
    int xcd = bid & 7;
    int i = bid >> 3;                 // 0..383
    int z, xb;
    if (i < 128) { z = 0; xb = xcd * 128 + i; }
    else { int j = i - 128; z = 1 + (j & 1); xb = xcd * 128 + (j >> 1); }

    const float* A  = (z == 0) ? x : ctx;
    const _Float16* WT = wt + (size_t)z * 36864;
    const float* bias = (z == 0) ? bq : (z == 1 ? bk : bv);
    _Float16* outp = (z == 0) ? qh : (z == 1 ? kh : vh);
    float scale = (z == 0) ? SCALE : 1.f;

    __shared__ _Float16 As[128][LDK];

    int t = threadIdx.x;
    int m0 = xb * 128;
    int b  = m0 / NPIX;
    int p0 = m0 % NPIX;
    const float* Ab = A + (size_t)b * 192 * NPIX + p0;

    int lane = t & 63;
    int wid  = t >> 6;
    int wm = wid & 1;         // 2 m-halves of 64 pixels
    int wn = wid >> 1;        // 4 n-quarters of 48 channels
    int lq = lane & 15;
    int lk = lane >> 4;

    // staging: thread handles (p=t&127, cq=t>>7) and (p, cq+4); 4 channels per task
    int cq0 = t >> 7, pp = t & 127;

    float ra[2][8];
    f4 acc[12] = {};

    {   // prologue load ks=0
        #pragma unroll
        for (int j = 0; j < 4; j++) ra[0][j]     = Ab[(size_t)(4 * cq0 + j) * NPIX + pp];
        #pragma unroll
        for (int j = 0; j < 4; j++) ra[0][4 + j] = Ab[(size_t)(4 * (cq0 + 4) + j) * NPIX + pp];
    }

    #pragma unroll
    for (int ks = 0; ks < 6; ks++) {
        int cur = ks & 1;
        if (ks) __syncthreads();      // prev compute done before overwrite
        {
            U4 u;
            u.p2[0] = __builtin_amdgcn_cvt_pkrtz(ra[cur][0], ra[cur][1]);
            u.p2[1] = __builtin_amdgcn_cvt_pkrtz(ra[cur][2], ra[cur][3]);
            *(f16x4*)&As[pp][4 * cq0] = u.v4;
            u.p2[0] = __builtin_amdgcn_cvt_pkrtz(ra[cur][4], ra[cur][5]);
            u.p2[1] = __builtin_amdgcn_cvt_pkrtz(ra[cur][6], ra[cur][7]);
            *(f16x4*)&As[pp][4 * (cq0 + 4)] = u.v4;
        }
        if (ks < 5) {
            int k0 = (ks + 1) * 32;
            #pragma unroll
            for (int j = 0; j < 4; j++) ra[cur ^ 1][j]     = Ab[(size_t)(k0 + 4 * cq0 + j) * NPIX + pp];
            #pragma unroll
            for (int j = 0; j < 4; j++) ra[cur ^ 1][4 + j] = Ab[(size_t)(k0 + 4 * (cq0 + 4) + j) * NPIX + pp];
        }
        __syncthreads();

        f16x8 wf[3];
        #pragma unroll
        for (int ni = 0; ni < 3; ni++)
            wf[ni] = *(const f16x8*)&WT[(size_t)(wn * 48 + ni * 16 + lq) * 192 + ks * 32 + lk * 8];
        #pragma unroll
        for (int mi = 0; mi < 4; mi++) {
            f16x8 pfr = *(const f16x8*)&As[wm * 64 + mi * 16 + lq][lk * 8];
            #pragma unroll
            for (int ni = 0; ni < 3; ni++)
                acc[mi * 3 + ni] = __builtin_amdgcn_mfma_f32_16x16x32_f16(wf[ni], pfr, acc[mi * 3 + ni], 0, 0, 0);
        }
    }

    // epilogue: lane owns pixel (col) and 4 consecutive channels (rows) -> 8B stores
    #pragma unroll
    for (int mi = 0; mi < 4; mi++) {
        int p = p0 + wm * 64 + mi * 16 + lq;
        #pragma unroll
        for (int ni = 0; ni < 3; ni++) {
            int n0 = wn * 48 + ni * 16 + lk * 4;
            int g = n0 >> 5, d0 = n0 & 31;
            f4 v = acc[mi * 3 + ni];
            U4 u;
            u.p2[0] = __builtin_amdgcn_cvt_pkrtz((v[0] + bias[n0]) * scale,     (v[1] + bias[n0 + 1]) * scale);
            u.p2[1] = __builtin_amdgcn_cvt_pkrtz((v[2] + bias[n0 + 2]) * scale, (v[3] + bias[n0 + 3]) * scale);
            *(f16x4*)(outp + ((size_t)(b * NHEADS + g) * NPIX + p) * HD + d0) = u.v4;
        }
    }
}

// ---------------- MFMA neighborhood attention (unchanged from R6/R7) ----------------
#define KS_ELE 33280            // 26*32*40 fp16
#define NA2D_SMEM 134912

template<int K>
__device__ __forceinline__ void na2d_tile(
    const _Float16* __restrict__ qh, const _Float16* __restrict__ kh,
    const _Float16* __restrict__ vh, const float* __restrict__ rpb,
    _Float16* __restrict__ ah, char* smem, int b, int g_head, int hi, int ty, int tx)
{
    constexpr int NS = K / 2;
    constexpr int RW = 2 * K - 1;
    _Float16* Ks = (_Float16*)smem;
    _Float16* Vt = Ks + KS_ELE;
    float* rpbs = (float*)(smem + 2 * KS_ELE * 2);

    int t = threadIdx.x;
    size_t plane = (size_t)(b * NHEADS + g_head) * NPIX;
    int h0 = ty * 16, w0 = tx * 16;
    int rmin = min(max(h0 - NS, 0), HH - K);
    int rtop = min(max(h0 + 15 - NS, 0), HH - K);
    int rows_n = rtop + K - rmin;
    int cwin0 = min(max(w0 - NS, 0), WW - K);
    int ctop = min(max(w0 + 15 - NS, 0), WW - K);
    int cols_n = ctop + K - cwin0;

    for (int i = t; i < RW * RW; i += 512) rpbs[i] = rpb[(size_t)hi * RW * RW + i];

    int ntask = rows_n * 128;
    for (int idx = t; idx < ntask; idx += 512) {
        int row = idx >> 7;
        int key = (idx >> 2) & 31;
        int dc  = idx & 3;
        f16x8 kv = {0,0,0,0,0,0,0,0};
        f16x8 vvv = {0,0,0,0,0,0,0,0};
        if (key < cols_n) {
            size_t pix = plane + (size_t)(rmin + row) * WW + (cwin0 + key);
            kv = *(const f16x8*)&kh[pix * HD + dc * 8];
            vvv = *(const f16x8*)&vh[pix * HD + dc * 8];
        }
        *(f16x8*)&Ks[row * 1280 + key * LDK + dc * 8] = kv;
        int m = 8 * ((key & 15) >> 2) + 4 * (key >> 4) + (key & 3);
        #pragma unroll
        for (int j = 0; j < 8; j++)
            Vt[row * 1280 + (dc * 8 + j) * LDK + m] = vvv[j];
    }
    __syncthreads();

    int lane = t & 63, wid = t >> 6;
    int lq = lane & 15, lg = lane >> 4;
    int wq = w0 + lq;
    int c0q = min(max(wq - NS, 0), WW - K);
    int klo = c0q - cwin0;
    int shiftc = cwin0 - wq + K - 1;
    f4 zf4 = {0.f, 0.f, 0.f, 0.f};

    #pragma unroll 1
    for (int qi = 0; qi < 2; qi++) {
        int qr = wid * 2 + qi;
        int h = h0 + qr;
        int r0q = min(max(h - NS, 0), HH - K);
        int row_base = r0q - rmin;
        f16x8 qf = *(const f16x8*)&qh[(plane + (size_t)h * WW + w0 + lq) * HD + lg * 8];
        f4 acc0 = zf4, acc1 = zf4;
        float lsum = 0.f;

        #pragma unroll 1
        for (int ki = 0; ki < K; ki++) {
            int row = row_base + ki;
            const _Float16* kbase = &Ks[row * 1280 + lg * 8];
            f16x8 a0 = *(const f16x8*)&kbase[lq * LDK];
            f16x8 a1 = *(const f16x8*)&kbase[(16 + lq) * LDK];
            f4 s0 = __builtin_amdgcn_mfma_f32_16x16x32_f16(a0, qf, zf4, 0, 0, 0);
            f4 s1 = __builtin_amdgcn_mfma_f32_16x16x32_f16(a1, qf, zf4, 0, 0, 0);

            int rel_r = r0q + ki - h + K - 1;
            const float* rrow = rpbs + rel_r * RW;
            float pf[2][4];
            #pragma unroll
            for (int c = 0; c < 2; c++) {
                #pragma unroll
                for (int r = 0; r < 4; r++) {
                    int key_local = c * 16 + 4 * lg + r;
                    int rc = key_local + shiftc;
                    rc = min(max(rc, 0), RW - 1);
                    float biasv = rrow[rc];
                    bool valid = (unsigned)(key_local - klo) < (unsigned)K;
                    float sv = (c ? s1[r] : s0[r]) + biasv;
                    float pv = valid ? __expf(sv) : 0.f;
                    pf[c][r] = pv;
                    lsum += pv;
                }
            }
            union { g2 p[4]; f16x8 v; } P;
            P.p[0] = __builtin_amdgcn_cvt_pkrtz(pf[0][0], pf[0][1]);
            P.p[1] = __builtin_amdgcn_cvt_pkrtz(pf[0][2], pf[0][3]);
            P.p[2] = __builtin_amdgcn_cvt_pkrtz(pf[1][0], pf[1][1]);
            P.p[3] = __builtin_amdgcn_cvt_pkrtz(pf[1][2], pf[1][3]);

            const _Float16* vbase = &Vt[row * 1280 + lg * 8];
            f16x8 b0 = *(const f16x8*)&vbase[lq * LDK];
            f16x8 b1 = *(const f16x8*)&vbase[(16 + lq) * LDK];
            acc0 = __builtin_amdgcn_mfma_f32_16x16x32_f16(P.v, b0, acc0, 0, 0, 0);
            acc1 = __builtin_amdgcn_mfma_f32_16x16x32_f16(P.v, b1, acc1, 0, 0, 0);
        }

        lsum += __shfl_xor(lsum, 16);
        lsum += __shfl_xor(lsum, 32);
        float inv = 1.f / lsum;
        _Float16* obase = ah + (plane + (size_t)h * WW + w0) * HD;
        #pragma unroll
        for (int r = 0; r < 4; r++) {
            float ir = __shfl(inv, 4 * lg + r);
            obase[(4 * lg + r) * HD + lq]      = (_Float16)(acc0[r] * ir);
            obase[(4 * lg + r) * HD + lq + 16] = (_Float16)(acc1[r] * ir);
        }
    }
}

__global__ __launch_bounds__(512) void na2d_mfma(
    const _Float16* __restrict__ qh, const _Float16* __restrict__ kh,
    const _Float16* __restrict__ vh,
    const float* __restrict__ rpb0, const float* __restrict__ rpb1,
    const float* __restrict__ rpb2, _Float16* __restrict__ ah)
{
    extern __shared__ char smem[];
    int bid = blockIdx.x;
    int xcd = bid & 7;
    int i = bid >> 3;
    int phase = i >> 7;
    int j = i & 127;
    int lb = xcd * 128 + j;
    int bz = lb >> 6;
    int tile = lb & 63;
    int b = bz >> 1, hi = bz & 1;
    int ty = tile >> 3, tx = tile & 7;
    if (phase == 0)      na2d_tile<7>(qh, kh, vh, rpb0, ah, smem, b, 0 + hi, hi, ty, tx);
    else if (phase == 1) na2d_tile<9>(qh, kh, vh, rpb1, ah, smem, b, 2 + hi, hi, ty, tx);
    else                 na2d_tile<11>(qh, kh, vh, rpb2, ah, smem, b, 4 + hi, hi, ty, tx);
}

// ---------------- MFMA output projection (unchanged from R6/R7) ----------------
__global__ __launch_bounds__(512) void oproj_mfma(
    const _Float16* __restrict__ ah, const float* __restrict__ Wo,
    const float* __restrict__ bo, float* __restrict__ outp)
{
    __shared__ _Float16 Ws[192][LDK];

    int t = threadIdx.x;
    int m0 = blockIdx.x * 128;
    int b  = m0 / NPIX;
    int p0 = m0 % NPIX;

    int lane = t & 63;
    int wid  = t >> 6;
    int wm = wid & 1;
    int wn = wid >> 1;
    int lr = lane & 15;
    int lk = lane >> 4;

    f4 acc[4][3] = {};

    for (int ks = 0; ks < 6; ks++) {
        int k0 = ks * 32;
        #pragma unroll
        for (int i = 0; i < 12; i++) {
            int s = t + i * 512;
            int c = s / 192, n = s - c * 192;
            Ws[n][c] = (_Float16)Wo[(size_t)(k0 + c) * 192 + n];
        }
        __syncthreads();

        const _Float16* abase = ah + (size_t)(b * NHEADS + ks) * NPIX * HD;
        f16x8 af[4], bf[3];
        #pragma unroll
        for (int mi = 0; mi < 4; mi++)
            af[mi] = *(const f16x8*)&abase[(size_t)(p0 + wm * 64 + mi * 16 + lr) * HD + lk * 8];
        #pragma unroll
        for (int ni = 0; ni < 3; ni++)
            bf[ni] = *(const f16x8*)&Ws[wn * 48 + ni * 16 + lr][lk * 8];
        #pragma unroll
        for (int mi = 0; mi < 4; mi++)
            #pragma unroll
            for (int ni = 0; ni < 3; ni++)
                acc[mi][ni] = __builtin_amdgcn_mfma_f32_16x16x32_f16(af[mi], bf[ni], acc[mi][ni], 0, 0, 0);
        __syncthreads();
    }

    #pragma unroll
    for (int ni = 0; ni < 3; ni++) {
        int n = wn * 48 + ni * 16 + lr;
        float bb = bo[n];
        float* obase = outp + ((size_t)b * 192 + n) * NPIX + p0 + wm * 64;
        #pragma unroll
        for (int mi = 0; mi < 4; mi++) {
            f4 v = acc[mi][ni];
            v[0] += bb; v[1] += bb; v[2] += bb; v[3] += bb;
            *(f4*)&obase[mi * 16 + lk * 4] = v;
        }
    }
}

extern "C" void kernel_launch(void* const* d_in, const int* in_sizes, int n_in,
                              void* d_out, int out_size, void* d_ws, size_t ws_size,
                              hipStream_t stream) {
    const float* x    = (const float*)d_in[0];
    const float* ctx  = (const float*)d_in[1];
    const float* Wq   = (const float*)d_in[2];
    const float* bq   = (const float*)d_in[3];
    const float* Wk   = (const float*)d_in[4];
    const float* bk   = (const float*)d_in[5];
    const float* Wv   = (const float*)d_in[6];
    const float* bv   = (const float*)d_in[7];
    const float* Wo   = (const float*)d_in[8];
    const float* bo   = (const float*)d_in[9];
    const float* rpb0 = (const float*)d_in[10];
    const float* rpb1 = (const float*)d_in[11];
    const float* rpb2 = (const float*)d_in[12];

    size_t N = (size_t)NB * NHEADS * NPIX * HD;
    _Float16* qh = (_Float16*)d_ws;
    _Float16* kh = qh + N;
    _Float16* vh = kh + N;
    _Float16* ah = vh + N;
    _Float16* wt = ah;   // park fp16 WT (3*36864 elems = 221KB) in ah; na2d overwrites later
    float* outp = (float*)d_out;

    (void)hipFuncSetAttribute((const void*)na2d_mfma,
                              hipFuncAttributeMaxDynamicSharedMemorySize, NA2D_SMEM);

    prep_wt<<<216, 512, 0, stream>>>(Wq, Wk, Wv, wt);
    proj_mfma<<<3072, 512, 0, stream>>>(x, ctx, wt, bq, bk, bv, qh, kh, vh);
    na2d_mfma<<<3072, 512, NA2D_SMEM, stream>>>(qh, kh, vh, rpb0, rpb1, rpb2, ah);
    oproj_mfma<<<1024, 512, 0, stream>>>(ah, Wo, bo, outp);
}